// Round 1
// baseline (142.960 us; speedup 1.0000x reference)
//
#include <hip/hip_runtime.h>
#include <math.h>

#define NS 1000
#define NV 200
#define NF 5
#define NK 80
#define EPSF 1e-5f

// fp32(2*pi) = 0x40C90FDB; reference wraps with jnp.mod(x, 2pi) in f32.
#define TWOPI_F 6.28318530717958647692f
// fp32(2*pi/16) -- the scan multiplies fp32(j) by this constant.
#define STEP_F  0.39269908169872414f

static __device__ __forceinline__ float frcp(float v) {
    return __builtin_amdgcn_rcpf(v);
}

// One block per sample. 128 threads.
// Phase 1: per-vertex tables -> LDS (12 floats per vertex).
// Phase 2: thread = (j, t-pair): j = tid>>3 (rotation), tp = tid&7 (theta bins 2tp, 2tp+1).
//          Accumulate desc[f][r][2] over vertices (50 fp32 regs).
// Phase 3: desc -> LDS (16 x 5 x 80 = 25.6 KB, reuses phase-1 space).
// Phase 4: thread = (f, jout-quad): cf = desc . W, max over 16 rotations, +b, relu,
//          store out[s][jout][f].
__global__ __launch_bounds__(128) void lsres_fused(
        const float* __restrict__ x,
        const float* __restrict__ mu_rho,
        const float* __restrict__ sigma_rho,
        const float* __restrict__ mu_theta,
        const float* __restrict__ sigma_theta,
        const float* __restrict__ Wc,
        const float* __restrict__ bc,
        float* __restrict__ out) {
    // 1600 float4 = 25.6 KB. First 600 float4 (= NV*3) hold the phase-1/2 vertex
    // tables; after a barrier the whole array is reused for desc[16][5][80].
    __shared__ float4 smem4[1600];
    float* smem = (float*)smem4;

    const int s   = blockIdx.x;
    const int tid = threadIdx.x;
    const int j   = tid >> 3;   // rotation 0..15
    const int tp  = tid & 7;    // theta-pair 0..7
    const int t0  = tp * 2;     // theta bins t0, t0+1

    // --- per-thread constants (theta-bin Gaussians; F rows are identical tiles) ---
    const float mu0 = mu_theta[t0];
    const float mu1 = mu_theta[t0 + 1];
    const float sg0 = sigma_theta[t0];
    const float sg1 = sigma_theta[t0 + 1];
    const float ist0 = 1.0f / (sg0 * sg0 + EPSF);
    const float ist1 = 1.0f / (sg1 * sg1 + EPSF);
    const float joff = (float)j * STEP_F;

    float mr[5], isr[5];
#pragma unroll
    for (int r = 0; r < 5; ++r) {
        mr[r] = mu_rho[r * 16];             // mu_rho[k] depends only on r = k/16
        float sr = sigma_rho[r * 16];
        isr[r] = 1.0f / (sr * sr + EPSF);
    }

    // --- Phase 1: vertex tables ---
    for (int v = tid; v < NV; v += 128) {
        const float* xe = x + ((size_t)s * NV + v) * 8;
        float4 x0 = *(const float4*)(xe);       // feat0..3
        float4 x1 = *(const float4*)(xe + 4);   // feat4, rho, theta, mask
        float rho = x1.y, theta = x1.z, mask = x1.w;
        float rg[5];
        float srg = 0.0f;
#pragma unroll
        for (int r = 0; r < 5; ++r) {
            float d = rho - mr[r];
            rg[r] = __expf(-d * d * isr[r]);
            srg += rg[r];
        }
        // act_norm = mask*Rg*T / (mask*sumRg*sumT + eps); fold mask into feat and denom.
        smem4[v * 3 + 0] = make_float4(x0.x * mask, x0.y * mask, x0.z * mask, x0.w * mask);
        smem4[v * 3 + 1] = make_float4(x1.x * mask, rg[0], rg[1], rg[2]);
        smem4[v * 3 + 2] = make_float4(rg[3], rg[4], mask * srg, theta);
    }
    __syncthreads();

    // --- Phase 2: accumulate desc over vertices ---
    float acc[5][5][2];
#pragma unroll
    for (int f = 0; f < 5; ++f)
#pragma unroll
        for (int r = 0; r < 5; ++r) {
            acc[f][r][0] = 0.0f;
            acc[f][r][1] = 0.0f;
        }

    for (int v = 0; v < NV; ++v) {
        float4 a  = smem4[v * 3 + 0];   // fm0..3
        float4 bv = smem4[v * 3 + 1];   // fm4, rg0..2
        float4 c  = smem4[v * 3 + 2];   // rg3, rg4, mask*sumRg, theta

        // th = mod(theta + j*step, 2pi), matching the reference's f32 wrap decision.
        float th = c.w + joff;
        th = (th >= TWOPI_F) ? (th - TWOPI_F) : th;

        float d0 = th - mu0;
        float d1 = th - mu1;
        float T0 = __expf(-d0 * d0 * ist0);
        float T1 = __expf(-d1 * d1 * ist1);

        // sum of T over the 16 theta bins of this rotation j (8-lane group, 2 bins each)
        float sT = T0 + T1;
        sT += __shfl_xor(sT, 1);
        sT += __shfl_xor(sT, 2);
        sT += __shfl_xor(sT, 4);

        float inv = frcp(fmaf(c.z, sT, EPSF));
        float p0 = T0 * inv;
        float p1 = T1 * inv;

        float fm[5] = {a.x, a.y, a.z, a.w, bv.x};
        float rg[5] = {bv.y, bv.z, bv.w, c.x, c.y};
#pragma unroll
        for (int r = 0; r < 5; ++r) {
            float g0 = rg[r] * p0;
            float g1 = rg[r] * p1;
#pragma unroll
            for (int f = 0; f < 5; ++f) {
                acc[f][r][0] = fmaf(fm[f], g0, acc[f][r][0]);
                acc[f][r][1] = fmaf(fm[f], g1, acc[f][r][1]);
            }
        }
    }
    __syncthreads();   // everyone done reading the vertex tables

    // --- Phase 3: desc -> LDS, layout desc[j][f][k], k = r*16 + t ---
    {
        float2* sd2 = (float2*)smem;
#pragma unroll
        for (int f = 0; f < 5; ++f)
#pragma unroll
            for (int r = 0; r < 5; ++r) {
                int idx = (j * 5 + f) * 80 + r * 16 + t0;   // even
                sd2[idx >> 1] = make_float2(acc[f][r][0], acc[f][r][1]);
            }
    }
    __syncthreads();

    // --- Phase 4: cf = desc . W, max over rotations, +b, relu ---
    if (tid < 100) {
        const int f  = tid / 20;
        const int jq = tid % 20;
        const int jo = jq * 4;          // output bins jo..jo+3

        float a2[16][4];
#pragma unroll
        for (int jj = 0; jj < 16; ++jj)
#pragma unroll
            for (int q = 0; q < 4; ++q) a2[jj][q] = 0.0f;

        const float* Wf = Wc + f * (NK * NK);
        for (int k4 = 0; k4 < 20; ++k4) {
            const float* wp = Wf + (k4 * 4) * NK + jo;
            float4 w0 = *(const float4*)(wp);
            float4 w1 = *(const float4*)(wp + NK);
            float4 w2 = *(const float4*)(wp + 2 * NK);
            float4 w3 = *(const float4*)(wp + 3 * NK);
#pragma unroll
            for (int jj = 0; jj < 16; ++jj) {
                float4 d4 = smem4[(jj * 5 + f) * 20 + k4];
                a2[jj][0] = fmaf(d4.x, w0.x, a2[jj][0]);
                a2[jj][0] = fmaf(d4.y, w1.x, a2[jj][0]);
                a2[jj][0] = fmaf(d4.z, w2.x, a2[jj][0]);
                a2[jj][0] = fmaf(d4.w, w3.x, a2[jj][0]);
                a2[jj][1] = fmaf(d4.x, w0.y, a2[jj][1]);
                a2[jj][1] = fmaf(d4.y, w1.y, a2[jj][1]);
                a2[jj][1] = fmaf(d4.z, w2.y, a2[jj][1]);
                a2[jj][1] = fmaf(d4.w, w3.y, a2[jj][1]);
                a2[jj][2] = fmaf(d4.x, w0.z, a2[jj][2]);
                a2[jj][2] = fmaf(d4.y, w1.z, a2[jj][2]);
                a2[jj][2] = fmaf(d4.z, w2.z, a2[jj][2]);
                a2[jj][2] = fmaf(d4.w, w3.z, a2[jj][2]);
                a2[jj][3] = fmaf(d4.x, w0.w, a2[jj][3]);
                a2[jj][3] = fmaf(d4.y, w1.w, a2[jj][3]);
                a2[jj][3] = fmaf(d4.z, w2.w, a2[jj][3]);
                a2[jj][3] = fmaf(d4.w, w3.w, a2[jj][3]);
            }
        }

        float m[4] = {-INFINITY, -INFINITY, -INFINITY, -INFINITY};
#pragma unroll
        for (int jj = 0; jj < 16; ++jj)
#pragma unroll
            for (int q = 0; q < 4; ++q) m[q] = fmaxf(m[q], a2[jj][q]);

#pragma unroll
        for (int q = 0; q < 4; ++q) {
            float val = fmaxf(m[q] + bc[f * NK + jo + q], 0.0f);
            // out[s][jout][f], jout = jo+q
            out[(size_t)s * (NK * NF) + (jo + q) * NF + f] = val;
        }
    }
}

extern "C" void kernel_launch(void* const* d_in, const int* in_sizes, int n_in,
                              void* d_out, int out_size, void* d_ws, size_t ws_size,
                              hipStream_t stream) {
    const float* x           = (const float*)d_in[0];
    const float* mu_rho      = (const float*)d_in[1];
    const float* sigma_rho   = (const float*)d_in[2];
    const float* mu_theta    = (const float*)d_in[3];
    const float* sigma_theta = (const float*)d_in[4];
    const float* Wc          = (const float*)d_in[5];
    const float* bc          = (const float*)d_in[6];
    float* out = (float*)d_out;

    lsres_fused<<<dim3(NS), dim3(128), 0, stream>>>(
        x, mu_rho, sigma_rho, mu_theta, sigma_theta, Wc, bc, out);
}